// Round 9
// baseline (237.664 us; speedup 1.0000x reference)
//
#include <hip/hip_runtime.h>

typedef _Float16 half8 __attribute__((ext_vector_type(8)));
typedef _Float16 half4_t __attribute__((ext_vector_type(4)));
typedef float f32x4 __attribute__((ext_vector_type(4)));

#define NBATCH 2048
#define NA 64
#define SA 128
#define HID 256

// LDS halves: RA 16384 (32KB): h1 -> z -> attn(frags 0..7)
//             RB 16384 (32KB): emb -> xg1 -> feat -> fg2
#define OFF_RA 0
#define OFF_RB 16384
#define SMEM_BYTES 65536

// packed fp16 weight offsets (halves) inside d_ws
#define W_ENC1 0
#define W_ENC2 (W_ENC1 + 128 * 256)
#define W_ATTN (W_ENC2 + 256 * 256)
#define W_GC1 (W_ATTN + 256 * 256)
#define W_NN1 (W_GC1 + 128 * 256)
#define W_GC2 (W_NN1 + 128 * 256)
#define W_NN2 (W_GC2 + 256 * 256)

#define MFMA(a, b, cacc) __builtin_amdgcn_mfma_f32_16x16x32_f16((a), (b), (cacc), 0, 0, 0)

// One launch packs all 7 weights into MFMA B-fragment order fp16.
// dst[((kt*16+nt)*64+lane)*8 + j] = W[kt*32 + (lane>>4)*8 + j][nt*16 + (lane&15)]
__global__ void pack_all(const float* __restrict__ e1, const float* __restrict__ e2,
                         const float* __restrict__ aw, const float* __restrict__ g1,
                         const float* __restrict__ n1, const float* __restrict__ g2,
                         const float* __restrict__ n2, _Float16* __restrict__ dst) {
  int b = (int)blockIdx.x;
  const float* src;
  int off;
  if (b < 16) { src = e1; off = W_ENC1; }
  else if (b < 48) { src = e2; off = W_ENC2; b -= 16; }
  else if (b < 80) { src = aw; off = W_ATTN; b -= 48; }
  else if (b < 96) { src = g1; off = W_GC1; b -= 80; }
  else if (b < 112) { src = n1; off = W_NN1; b -= 96; }
  else if (b < 144) { src = g2; off = W_GC2; b -= 112; }
  else { src = n2; off = W_NN2; b -= 144; }
  int t = b * 256 + (int)threadIdx.x;
  int lane = t & 63, frag = t >> 6;
  int nt = frag & 15, kt = frag >> 4;
  int g = lane >> 4, c = lane & 15;
  half8 h;
#pragma unroll
  for (int j = 0; j < 8; ++j)
    h[j] = (_Float16)src[(size_t)(kt * 32 + g * 8 + j) * 256 + nt * 16 + c];
  *(half8*)(dst + off + (size_t)t * 8) = h;
}

__global__ __launch_bounds__(512, 2) void dicg_main(
    const float* __restrict__ x, const float* __restrict__ b_enc1,
    const float* __restrict__ b_enc2, const float* __restrict__ b_gc1,
    const float* __restrict__ b_nn1, const float* __restrict__ b_gc2,
    const float* __restrict__ b_nn2, const _Float16* __restrict__ wp,
    float* __restrict__ out, float* __restrict__ attn_out) {
  extern __shared__ _Float16 sm[];
  _Float16* RA = sm + OFF_RA;   // h1 -> z -> attn A-frags (0..7)
  _Float16* RB = sm + OFF_RB;   // emb -> xg1 -> feat -> fg2

  const int tid = (int)threadIdx.x;
  const int wv = tid >> 6;   // wave 0..7
  const int lane = tid & 63;
  const int g = lane >> 4;   // 0..3
  const int c = lane & 15;   // 0..15
  const int wb = wv - 4;     // chain-B wave index (wv>=4)
  const int bb = (int)blockIdx.x;
  const float* __restrict__ xb = x + (size_t)bb * (NA * SA);

  // ---- fragment-linear LDS loads (conflict-free: lane*16B contiguous) ----
  auto ldA = [&](const _Float16* p, int kt, int rt) -> half8 {
    return *(const half8*)(p + (kt * 4 + rt) * 512 + lane * 8);
  };
  auto ldB = [&](const _Float16* p, int kt, int ct) -> half8 {
    return *(const half8*)(p + (kt * 16 + ct) * 512 + lane * 8);
  };
  auto wfrag = [&](const _Float16* wbp, int kt, int ntg) -> half8 {
    return *(const half8*)(wbp + ((size_t)(kt * 16 + ntg) * 64 + lane) * 8);
  };
  auto xfrag = [&](int r0, int k0) -> half8 {
    const float* p = xb + (r0 + c) * SA + k0 + g * 8;
    f32x4 u = *(const f32x4*)p;
    f32x4 v = *(const f32x4*)(p + 4);
    half8 h;
    h[0] = (_Float16)u[0]; h[1] = (_Float16)u[1];
    h[2] = (_Float16)u[2]; h[3] = (_Float16)u[3];
    h[4] = (_Float16)v[0]; h[5] = (_Float16)v[1];
    h[6] = (_Float16)v[2]; h[7] = (_Float16)v[3];
    return h;
  };

  // ---- C-layout -> packed-LDS stores ----
  // 32-col (8-way split): lane holds D[16rt+4g+r][32wv+16nt+c], nt<2
  auto stA32 = [&](_Float16* dst, int rt, int nt, int r, float v) {
    int lanep = (2 * nt + (c >> 3)) * 16 + 4 * g + r;
    dst[(wv * 4 + rt) * 512 + lanep * 8 + (c & 7)] = (_Float16)v;
  };
  // 64-col (4-way split, base wave w4): lane holds D[16rt+4g+r][64w4+16nt+c], nt<4
  auto stA64 = [&](_Float16* dst, int w4, int rt, int nt, int r, float v) {
    int kt = 2 * w4 + (nt >> 1);
    int lanep = (2 * (nt & 1) + (c >> 3)) * 16 + 4 * g + r;
    dst[(kt * 4 + rt) * 512 + lanep * 8 + (c & 7)] = (_Float16)v;
  };
  // B-packed stores (vector half4)
  auto stB64 = [&](_Float16* dst, int rt, int nt, half4_t h) {  // waves B, 64-col
    int fi = (rt >> 1) * 16 + 4 * wb + nt;
    int lanep = (2 * (rt & 1) + (g >> 1)) * 16 + c;
    *(half4_t*)(dst + fi * 512 + lanep * 8 + 4 * (g & 1)) = h;
  };
  auto stB32 = [&](_Float16* dst, int rt, int nt, half4_t h) {  // all, 32-col
    int fi = (rt >> 1) * 16 + 2 * wv + nt;
    int lanep = (2 * (rt & 1) + (g >> 1)) * 16 + c;
    *(half4_t*)(dst + fi * 512 + lanep * 8 + 4 * (g & 1)) = h;
  };

  // chain-B register-held results (waves 4..7 only)
  half4_t xgh[4][4];   // xg1 + bias (no relu)
  half4_t nn1h[4][4];  // relu(x@nn1+b)
  half4_t r2h[4][2];   // relu(feat@nn2+b), all waves (32-col)

  // ========== P1 (all 8, 32-col): h1 = relu(x@enc1+b1) -> RA ==========
  {
    f32x4 acc[4][2]{};
#pragma unroll
    for (int kt = 0; kt < 4; ++kt) {
      half8 af[4], bf[2];
#pragma unroll
      for (int rt = 0; rt < 4; ++rt) af[rt] = xfrag(16 * rt, kt * 32);
#pragma unroll
      for (int nt = 0; nt < 2; ++nt) bf[nt] = wfrag(wp + W_ENC1, kt, 2 * wv + nt);
#pragma unroll
      for (int rt = 0; rt < 4; ++rt)
#pragma unroll
        for (int nt = 0; nt < 2; ++nt) acc[rt][nt] = MFMA(af[rt], bf[nt], acc[rt][nt]);
    }
#pragma unroll
    for (int nt = 0; nt < 2; ++nt) {
      float bv = b_enc1[32 * wv + 16 * nt + c];
#pragma unroll
      for (int rt = 0; rt < 4; ++rt)
#pragma unroll
        for (int r = 0; r < 4; ++r)
          stA32(RA, rt, nt, r, fmaxf(acc[rt][nt][r] + bv, 0.f));
    }
  }
  __syncthreads();  // B1: h1 visible
  // ========== P2 (all 8, 32-col): emb = relu(h1@enc2+b2) -> RB ==========
  {
    f32x4 acc[4][2]{};
#pragma unroll
    for (int kt = 0; kt < 8; ++kt) {
      half8 af[4], bf[2];
#pragma unroll
      for (int rt = 0; rt < 4; ++rt) af[rt] = ldA(RA, kt, rt);
#pragma unroll
      for (int nt = 0; nt < 2; ++nt) bf[nt] = wfrag(wp + W_ENC2, kt, 2 * wv + nt);
#pragma unroll
      for (int rt = 0; rt < 4; ++rt)
#pragma unroll
        for (int nt = 0; nt < 2; ++nt) acc[rt][nt] = MFMA(af[rt], bf[nt], acc[rt][nt]);
    }
#pragma unroll
    for (int nt = 0; nt < 2; ++nt) {
      float bv = b_enc2[32 * wv + 16 * nt + c];
#pragma unroll
      for (int rt = 0; rt < 4; ++rt)
#pragma unroll
        for (int r = 0; r < 4; ++r)
          stA32(RB, rt, nt, r, fmaxf(acc[rt][nt][r] + bv, 0.f));
    }
  }
  __syncthreads();  // B2: h1 reads done, emb visible
  // ===== P3 SPLIT: waves 0-3: z = emb@attn_w (64-col) -> RA (over h1)
  //                 waves 4-7: xg1, nn1 from global x -> registers =====
  if (wv < 4) {
    f32x4 acc[4][4]{};
#pragma unroll
    for (int kt = 0; kt < 8; ++kt) {
      half8 af[4], bf[4];
#pragma unroll
      for (int rt = 0; rt < 4; ++rt) af[rt] = ldA(RB, kt, rt);
#pragma unroll
      for (int nt = 0; nt < 4; ++nt) bf[nt] = wfrag(wp + W_ATTN, kt, 4 * wv + nt);
#pragma unroll
      for (int rt = 0; rt < 4; ++rt)
#pragma unroll
        for (int nt = 0; nt < 4; ++nt) acc[rt][nt] = MFMA(af[rt], bf[nt], acc[rt][nt]);
    }
#pragma unroll
    for (int nt = 0; nt < 4; ++nt)
#pragma unroll
      for (int rt = 0; rt < 4; ++rt)
#pragma unroll
        for (int r = 0; r < 4; ++r) stA64(RA, wv, rt, nt, r, acc[rt][nt][r]);
  } else {
    {  // xg1 = x@gc1 + b (64-col) -> regs
      f32x4 acc[4][4]{};
#pragma unroll
      for (int kt = 0; kt < 4; ++kt) {
        half8 af[4], bf[4];
#pragma unroll
        for (int rt = 0; rt < 4; ++rt) af[rt] = xfrag(16 * rt, kt * 32);
#pragma unroll
        for (int nt = 0; nt < 4; ++nt) bf[nt] = wfrag(wp + W_GC1, kt, 4 * wb + nt);
#pragma unroll
        for (int rt = 0; rt < 4; ++rt)
#pragma unroll
          for (int nt = 0; nt < 4; ++nt) acc[rt][nt] = MFMA(af[rt], bf[nt], acc[rt][nt]);
      }
#pragma unroll
      for (int nt = 0; nt < 4; ++nt) {
        float bv = b_gc1[64 * wb + 16 * nt + c];
#pragma unroll
        for (int rt = 0; rt < 4; ++rt)
#pragma unroll
          for (int r = 0; r < 4; ++r) xgh[rt][nt][r] = (_Float16)(acc[rt][nt][r] + bv);
      }
    }
    {  // nn1 = relu(x@nn1 + b) (64-col) -> regs
      f32x4 acc[4][4]{};
#pragma unroll
      for (int kt = 0; kt < 4; ++kt) {
        half8 af[4], bf[4];
#pragma unroll
        for (int rt = 0; rt < 4; ++rt) af[rt] = xfrag(16 * rt, kt * 32);
#pragma unroll
        for (int nt = 0; nt < 4; ++nt) bf[nt] = wfrag(wp + W_NN1, kt, 4 * wb + nt);
#pragma unroll
        for (int rt = 0; rt < 4; ++rt)
#pragma unroll
          for (int nt = 0; nt < 4; ++nt) acc[rt][nt] = MFMA(af[rt], bf[nt], acc[rt][nt]);
      }
#pragma unroll
      for (int nt = 0; nt < 4; ++nt) {
        float bv = b_nn1[64 * wb + 16 * nt + c];
#pragma unroll
        for (int rt = 0; rt < 4; ++rt)
#pragma unroll
          for (int r = 0; r < 4; ++r)
            nn1h[rt][nt][r] = (_Float16)fmaxf(acc[rt][nt][r] + bv, 0.f);
      }
    }
  }
  __syncthreads();  // B3: z visible (emb untouched)
  // ===== P4 (waves 0-3): scoresT = emb@zT, softmax, attn -> RA frags {wv,4+wv} =====
  if (wv < 4) {
    f32x4 sc[4]{};
#pragma unroll
    for (int kt = 0; kt < 8; ++kt) {
      half8 zbf = ldA(RA, kt, wv);  // zT B-operand: own 16 queries
#pragma unroll
      for (int mt = 0; mt < 4; ++mt) sc[mt] = MFMA(ldA(RB, kt, mt), zbf, sc[mt]);
    }
    // lane holds scoresT[m=16mt+4g+r][n=16wv+c]; softmax over m
    float m0 = sc[0][0];
#pragma unroll
    for (int mt = 0; mt < 4; ++mt)
#pragma unroll
      for (int r = 0; r < 4; ++r) m0 = fmaxf(m0, sc[mt][r]);
    m0 = fmaxf(m0, __shfl_xor(m0, 16));
    m0 = fmaxf(m0, __shfl_xor(m0, 32));
    float e[4][4], ssum = 0.f;
#pragma unroll
    for (int mt = 0; mt < 4; ++mt)
#pragma unroll
      for (int r = 0; r < 4; ++r) {
        e[mt][r] = __expf(sc[mt][r] - m0);
        ssum += e[mt][r];
      }
    ssum += __shfl_xor(ssum, 16);
    ssum += __shfl_xor(ssum, 32);
    float inv = 1.0f / ssum;
    float* ao = attn_out + ((size_t)bb * NA + 16 * wv + c) * NA;
#pragma unroll
    for (int mt = 0; mt < 4; ++mt) {
      f32x4 vv;
      half4_t hh;
#pragma unroll
      for (int r = 0; r < 4; ++r) {
        vv[r] = e[mt][r] * inv;
        hh[r] = (_Float16)vv[r];
      }
      *(f32x4*)(ao + 16 * mt + 4 * g) = vv;
      // attn -> RA frags {(mt>>1)*4+wv} = {wv, 4+wv}: own z frags, reads done
      int fi = (mt >> 1) * 4 + wv;
      int lanep = (2 * (mt & 1) + (g >> 1)) * 16 + c;
      *(half4_t*)(RA + fi * 512 + lanep * 8 + 4 * (g & 1)) = hh;
    }
  }
  __syncthreads();  // B4: emb/z reads done; attn visible; emb dead
  // ===== P5' (waves 4-7): write xg1 regs -> RB B-packed (over emb) =====
  if (wv >= 4) {
#pragma unroll
    for (int nt = 0; nt < 4; ++nt)
#pragma unroll
      for (int rt = 0; rt < 4; ++rt) stB64(RB, rt, nt, xgh[rt][nt]);
  }
  __syncthreads();  // B5: xg1 visible
  // ===== P6 (waves 4-7): feat = (relu(attn@xg1)+nn1)/64 -> RB (over xg1) =====
  {
    f32x4 a1[4][4]{};
    if (wv >= 4) {
#pragma unroll
      for (int kt = 0; kt < 2; ++kt) {
        half8 af[4], bf[4];
#pragma unroll
        for (int rt = 0; rt < 4; ++rt) af[rt] = ldA(RA, kt, rt);  // attn
#pragma unroll
        for (int nt = 0; nt < 4; ++nt) bf[nt] = ldB(RB, kt, 4 * wb + nt);
#pragma unroll
        for (int rt = 0; rt < 4; ++rt)
#pragma unroll
          for (int nt = 0; nt < 4; ++nt) a1[rt][nt] = MFMA(af[rt], bf[nt], a1[rt][nt]);
      }
    }
    __syncthreads();  // B6: all xg1 reads done
    if (wv >= 4) {
#pragma unroll
      for (int nt = 0; nt < 4; ++nt)
#pragma unroll
        for (int rt = 0; rt < 4; ++rt)
#pragma unroll
          for (int r = 0; r < 4; ++r)
            stA64(RB, wb, rt, nt, r,
                  (fmaxf(a1[rt][nt][r], 0.f) + (float)nn1h[rt][nt][r]) * 0.015625f);
    }
  }
  __syncthreads();  // B7: feat visible
  // ===== P7 (all 8, 32-col): nn2 -> regs; fg2 = feat@gc2+b -> RB (in-place) =====
  {
    f32x4 aN[4][2]{}, aG[4][2]{};
#pragma unroll
    for (int kt = 0; kt < 8; ++kt) {
      half8 af[4], b1[2], b2[2];
#pragma unroll
      for (int rt = 0; rt < 4; ++rt) af[rt] = ldA(RB, kt, rt);
#pragma unroll
      for (int nt = 0; nt < 2; ++nt) b1[nt] = wfrag(wp + W_NN2, kt, 2 * wv + nt);
#pragma unroll
      for (int nt = 0; nt < 2; ++nt) b2[nt] = wfrag(wp + W_GC2, kt, 2 * wv + nt);
#pragma unroll
      for (int rt = 0; rt < 4; ++rt)
#pragma unroll
        for (int nt = 0; nt < 2; ++nt) {
          aN[rt][nt] = MFMA(af[rt], b1[nt], aN[rt][nt]);
          aG[rt][nt] = MFMA(af[rt], b2[nt], aG[rt][nt]);
        }
    }
#pragma unroll
    for (int nt = 0; nt < 2; ++nt) {
      float bv = b_nn2[32 * wv + 16 * nt + c];
#pragma unroll
      for (int rt = 0; rt < 4; ++rt)
#pragma unroll
        for (int r = 0; r < 4; ++r)
          r2h[rt][nt][r] = (_Float16)fmaxf(aN[rt][nt][r] + bv, 0.f);
    }
    __syncthreads();  // B8: all feat reads done
#pragma unroll
    for (int nt = 0; nt < 2; ++nt) {
      float bv = b_gc2[32 * wv + 16 * nt + c];
#pragma unroll
      for (int rt = 0; rt < 4; ++rt) {
        half4_t h;
#pragma unroll
        for (int r = 0; r < 4; ++r) h[r] = (_Float16)(aG[rt][nt][r] + bv);
        stB32(RB, rt, nt, h);
      }
    }
  }
  __syncthreads();  // B9: fg2 visible
  // ===== P8 (all 8, 32-col): out = (relu(attn@fg2)+nn2)/64 -> global =====
  {
    f32x4 a1[4][2]{};
#pragma unroll
    for (int kt = 0; kt < 2; ++kt) {
      half8 af[4], bf[2];
#pragma unroll
      for (int rt = 0; rt < 4; ++rt) af[rt] = ldA(RA, kt, rt);  // attn
#pragma unroll
      for (int nt = 0; nt < 2; ++nt) bf[nt] = ldB(RB, kt, 2 * wv + nt);
#pragma unroll
      for (int rt = 0; rt < 4; ++rt)
#pragma unroll
        for (int nt = 0; nt < 2; ++nt) a1[rt][nt] = MFMA(af[rt], bf[nt], a1[rt][nt]);
    }
    float* ob = out + (size_t)bb * NA * HID;
#pragma unroll
    for (int nt = 0; nt < 2; ++nt)
#pragma unroll
      for (int rt = 0; rt < 4; ++rt)
#pragma unroll
        for (int r = 0; r < 4; ++r)
          ob[(size_t)(16 * rt + 4 * g + r) * HID + 32 * wv + 16 * nt + c] =
              (fmaxf(a1[rt][nt][r], 0.f) + (float)r2h[rt][nt][r]) * 0.015625f;
  }
}

extern "C" void kernel_launch(void* const* d_in, const int* in_sizes, int n_in,
                              void* d_out, int out_size, void* d_ws, size_t ws_size,
                              hipStream_t stream) {
  const float* x = (const float*)d_in[0];
  const float* enc_w1 = (const float*)d_in[1];
  const float* enc_b1 = (const float*)d_in[2];
  const float* enc_w2 = (const float*)d_in[3];
  const float* enc_b2 = (const float*)d_in[4];
  const float* attn_w = (const float*)d_in[5];
  const float* gc1_w = (const float*)d_in[6];
  const float* gc1_b = (const float*)d_in[7];
  const float* nn1_w = (const float*)d_in[8];
  const float* nn1_b = (const float*)d_in[9];
  const float* gc2_w = (const float*)d_in[10];
  const float* gc2_b = (const float*)d_in[11];
  const float* nn2_w = (const float*)d_in[12];
  const float* nn2_b = (const float*)d_in[13];
  // d_in[14] = n_agents (=64, compile-time constant)

  _Float16* wp = (_Float16*)d_ws;
  float* out = (float*)d_out;
  float* attn_o = out + (size_t)NBATCH * NA * HID;

  pack_all<<<176, 256, 0, stream>>>(enc_w1, enc_w2, attn_w, gc1_w, nn1_w, gc2_w,
                                    nn2_w, wp);
  dicg_main<<<NBATCH, 512, SMEM_BYTES, stream>>>(
      x, enc_b1, enc_b2, gc1_b, nn1_b, gc2_b, nn2_b, wp, out, attn_o);
}

// Round 10
// 156.413 us; speedup vs baseline: 1.5195x; 1.5195x over previous
//
#include <hip/hip_runtime.h>

typedef _Float16 half8 __attribute__((ext_vector_type(8)));
typedef _Float16 half4_t __attribute__((ext_vector_type(4)));
typedef float f32x4 __attribute__((ext_vector_type(4)));

#define NBATCH 2048
#define NA 64
#define SA 128
#define HID 256

// LDS halves: X 8192 (16KB) | R0 16384 (32KB) | ATT 8192 (16KB) = 65536 B
// ATT frags 0..7: attn A-frags; frags 8..15: per-wave q double-buffer slots.
#define OFF_X 0
#define OFF_R0 8192
#define OFF_ATT (8192 + 16384)
#define SMEM_BYTES ((8192 + 16384 + 8192) * 2)

// packed fp16 weight offsets (halves) inside d_ws
#define W_ENC1 0
#define W_ENC2 (W_ENC1 + 128 * 256)
#define W_ATTN (W_ENC2 + 256 * 256)
#define W_GC1 (W_ATTN + 256 * 256)
#define W_NN1 (W_GC1 + 128 * 256)
#define W_GC2 (W_NN1 + 128 * 256)
#define W_NN2 (W_GC2 + 256 * 256)

#define MFMA(a, b, cacc) __builtin_amdgcn_mfma_f32_16x16x32_f16((a), (b), (cacc), 0, 0, 0)

// lgkmcnt-only barrier. All cross-wave dataflow at these barriers is through
// LDS (lgkm-counted). __syncthreads would also drain vmcnt(0), killing any
// in-flight global weight prefetch; this keeps it alive across the barrier.
#define BAR()                                            \
  do {                                                   \
    asm volatile("s_waitcnt lgkmcnt(0)" ::: "memory");   \
    __builtin_amdgcn_s_barrier();                        \
  } while (0)

// One launch packs all 7 weights into MFMA B-fragment order fp16.
// dst[((kt*16+nt)*64+lane)*8 + j] = W[kt*32 + (lane>>4)*8 + j][nt*16 + (lane&15)]
__global__ void pack_all(const float* __restrict__ e1, const float* __restrict__ e2,
                         const float* __restrict__ aw, const float* __restrict__ g1,
                         const float* __restrict__ n1, const float* __restrict__ g2,
                         const float* __restrict__ n2, _Float16* __restrict__ dst) {
  int b = (int)blockIdx.x;
  const float* src;
  int off;
  if (b < 16) { src = e1; off = W_ENC1; }
  else if (b < 48) { src = e2; off = W_ENC2; b -= 16; }
  else if (b < 80) { src = aw; off = W_ATTN; b -= 48; }
  else if (b < 96) { src = g1; off = W_GC1; b -= 80; }
  else if (b < 112) { src = n1; off = W_NN1; b -= 96; }
  else if (b < 144) { src = g2; off = W_GC2; b -= 112; }
  else { src = n2; off = W_NN2; b -= 144; }
  int t = b * 256 + (int)threadIdx.x;
  int lane = t & 63, frag = t >> 6;
  int nt = frag & 15, kt = frag >> 4;
  int g = lane >> 4, c = lane & 15;
  half8 h;
#pragma unroll
  for (int j = 0; j < 8; ++j)
    h[j] = (_Float16)src[(size_t)(kt * 32 + g * 8 + j) * 256 + nt * 16 + c];
  *(half8*)(dst + off + (size_t)t * 8) = h;
}

__global__ __launch_bounds__(256, 2) void dicg_main(
    const float* __restrict__ x, const float* __restrict__ b_enc1,
    const float* __restrict__ b_enc2, const float* __restrict__ b_gc1,
    const float* __restrict__ b_nn1, const float* __restrict__ b_gc2,
    const float* __restrict__ b_nn2, const _Float16* __restrict__ wp,
    float* __restrict__ out, float* __restrict__ attn_out) {
  extern __shared__ _Float16 sm[];
  _Float16* X = sm + OFF_X;        // x fp16 A-frags (written P1, read P5)
  _Float16* R0 = sm + OFF_R0;      // h1 -> emb -> xg1T -> feat -> fg2T
  _Float16* ATTp = sm + OFF_ATT;   // frags 0..7: attn A-frags; 8..15: q dbuf

  const int tid = (int)threadIdx.x;
  const int wv = tid >> 6;   // wave 0..3 (owns output cols 64*wv..+63)
  const int lane = tid & 63;
  const int g = lane >> 4;   // 0..3
  const int c = lane & 15;   // 0..15
  const int bb = (int)blockIdx.x;
  const float* __restrict__ xb = x + (size_t)bb * (NA * SA);

  // ---- fragment-linear LDS loads (conflict-free: lane*16B contiguous) ----
  auto ldA = [&](const _Float16* p, int kt, int rt) -> half8 {
    return *(const half8*)(p + (kt * 4 + rt) * 512 + lane * 8);
  };
  auto ldB = [&](const _Float16* p, int kt, int ct) -> half8 {
    return *(const half8*)(p + (kt * 16 + ct) * 512 + lane * 8);
  };
  auto wfrag = [&](const _Float16* wb, int kt, int ntg) -> half8 {
    return *(const half8*)(wb + ((size_t)(kt * 16 + ntg) * 64 + lane) * 8);
  };
  auto xfrag = [&](int r0, int k0) -> half8 {
    const float* p = xb + (r0 + c) * SA + k0 + g * 8;
    f32x4 u = *(const f32x4*)p;
    f32x4 v = *(const f32x4*)(p + 4);
    half8 h;
    h[0] = (_Float16)u[0]; h[1] = (_Float16)u[1];
    h[2] = (_Float16)u[2]; h[3] = (_Float16)u[3];
    h[4] = (_Float16)v[0]; h[5] = (_Float16)v[1];
    h[6] = (_Float16)v[2]; h[7] = (_Float16)v[3];
    return h;
  };

  // ---- C-layout -> packed-LDS stores ----
  // producer lane holds D[16rt+4g+r][64wv+16nt+c]
  auto stA_val = [&](_Float16* dst, int rt, int nt, int r, float v) {
    int kt = 2 * wv + (nt >> 1);
    int lanep = (2 * (nt & 1) + (c >> 3)) * 16 + 4 * g + r;
    dst[(kt * 4 + rt) * 512 + lanep * 8 + (c & 7)] = (_Float16)v;
  };
  auto ep_storeA = [&](f32x4(&acc)[4][4], const float* bias, bool dorelu) {
#pragma unroll
    for (int nt = 0; nt < 4; ++nt) {
      float bv = bias[64 * wv + 16 * nt + c];
#pragma unroll
      for (int rt = 0; rt < 4; ++rt)
#pragma unroll
        for (int r = 0; r < 4; ++r) {
          float y = acc[rt][nt][r] + bv;
          if (dorelu) y = fmaxf(y, 0.f);
          stA_val(R0, rt, nt, r, y);
        }
    }
  };
  // B-packed store, vectorized: 4 consecutive halves per (rt,nt)
  auto ep_storeB = [&](f32x4(&acc)[4][4], const float* bias) {
#pragma unroll
    for (int nt = 0; nt < 4; ++nt) {
      float bv = bias[64 * wv + 16 * nt + c];
#pragma unroll
      for (int rt = 0; rt < 4; ++rt) {
        half4_t h;
#pragma unroll
        for (int r = 0; r < 4; ++r) h[r] = (_Float16)(acc[rt][nt][r] + bv);
        int fi = (rt >> 1) * 16 + 4 * wv + nt;
        int lanep = (2 * (rt & 1) + (g >> 1)) * 16 + c;
        *(half4_t*)(R0 + fi * 512 + lanep * 8 + 4 * (g & 1)) = h;
      }
    }
  };
  // q chunk C-layout -> per-wave double-buffered B-frag scratch (frags 8..15)
  auto stQ = [&](const f32x4(&q2)[2], int s) {
    _Float16* base = ATTp + (8 + 2 * wv + s) * 512;
#pragma unroll
    for (int nt2 = 0; nt2 < 2; ++nt2)
#pragma unroll
      for (int r = 0; r < 4; ++r)
        base[((2 * nt2 + (c >> 3)) * 16 + 4 * g + r) * 8 + (c & 7)] = (_Float16)q2[nt2][r];
  };
  auto mm_att = [&](f32x4(&acc)[4][4]) {
#pragma unroll
    for (int kt = 0; kt < 2; ++kt) {
      half8 af[4], bf[4];
#pragma unroll
      for (int rt = 0; rt < 4; ++rt) af[rt] = ldA(ATTp, kt, rt);
#pragma unroll
      for (int nt = 0; nt < 4; ++nt) bf[nt] = ldB(R0, kt, 4 * wv + nt);
#pragma unroll
      for (int rt = 0; rt < 4; ++rt)
#pragma unroll
        for (int nt = 0; nt < 4; ++nt) acc[rt][nt] = MFMA(af[rt], bf[nt], acc[rt][nt]);
    }
  };

  // cross-barrier weight prefetch registers
  half8 pf2[2][4];   // P2: W_ENC2 kt=0,1
  half8 pfq[4][2];   // P3: W_ATTN k2=0..3, cols 0,1 (q-tile 0)
  half8 pf5g[4], pf5n[4];        // P5: W_GC1 / W_NN1 kt=0
  half8 pf7n[2][4], pf7g[2][4];  // P7: W_NN2 / W_GC2 kt=0,1

  // ========== P1: h1 = relu(x@enc1+b1) -> R0; stage x fp16 frags -> X ==========
  {
    f32x4 acc[4][4]{};
#pragma unroll
    for (int kt = 0; kt < 4; ++kt) {
      half8 af[4], bf[4];
#pragma unroll
      for (int rt = 0; rt < 4; ++rt) af[rt] = xfrag(16 * rt, kt * 32);
#pragma unroll
      for (int nt = 0; nt < 4; ++nt) bf[nt] = wfrag(wp + W_ENC1, kt, 4 * wv + nt);
      if (kt == wv) {  // each wave stages one kt of x
#pragma unroll
        for (int rt = 0; rt < 4; ++rt)
          *(half8*)(X + (kt * 4 + rt) * 512 + lane * 8) = af[rt];
      }
#pragma unroll
      for (int rt = 0; rt < 4; ++rt)
#pragma unroll
        for (int nt = 0; nt < 4; ++nt) acc[rt][nt] = MFMA(af[rt], bf[nt], acc[rt][nt]);
    }
    // prefetch P2's first two K-tiles of W_ENC2 (consumed after B1)
#pragma unroll
    for (int s = 0; s < 2; ++s)
#pragma unroll
      for (int nt = 0; nt < 4; ++nt) pf2[s][nt] = wfrag(wp + W_ENC2, s, 4 * wv + nt);
    ep_storeA(acc, b_enc1, true);
  }
  BAR();  // B1
  // ========== P2: emb = relu(h1@enc2+b2), in-place ==========
  {
    f32x4 acc[4][4]{};
#pragma unroll
    for (int kt = 0; kt < 8; ++kt) {
      half8 af[4], bf[4];
#pragma unroll
      for (int rt = 0; rt < 4; ++rt) af[rt] = ldA(R0, kt, rt);
#pragma unroll
      for (int nt = 0; nt < 4; ++nt)
        bf[nt] = (kt < 2) ? pf2[kt][nt] : wfrag(wp + W_ENC2, kt, 4 * wv + nt);
#pragma unroll
      for (int rt = 0; rt < 4; ++rt)
#pragma unroll
        for (int nt = 0; nt < 4; ++nt) acc[rt][nt] = MFMA(af[rt], bf[nt], acc[rt][nt]);
    }
    // prefetch q-tile-0's first half of W_ATTN (consumed after B3)
#pragma unroll
    for (int k2 = 0; k2 < 4; ++k2) {
      pfq[k2][0] = wfrag(wp + W_ATTN, k2, 0);
      pfq[k2][1] = wfrag(wp + W_ATTN, k2, 1);
    }
    BAR();  // B2: all h1 reads done
    ep_storeA(acc, b_enc2, true);
  }
  BAR();  // B3
  // ===== P3+P4: scoresT = emb @ qT (q dbuf-pipelined), softmax =====
  {
    half8 aeK[8];
#pragma unroll
    for (int k2 = 0; k2 < 8; ++k2) aeK[k2] = ldA(R0, k2, wv);
    f32x4 sc[4]{};
    {
      f32x4 q2[2]{};
#pragma unroll
      for (int k2 = 0; k2 < 8; ++k2) {
        half8 b0 = (k2 < 4) ? pfq[k2][0] : wfrag(wp + W_ATTN, k2, 0);
        half8 b1 = (k2 < 4) ? pfq[k2][1] : wfrag(wp + W_ATTN, k2, 1);
        q2[0] = MFMA(aeK[k2], b0, q2[0]);
        q2[1] = MFMA(aeK[k2], b1, q2[1]);
      }
      stQ(q2, 0);
    }
#pragma unroll
    for (int ktp = 0; ktp < 8; ++ktp) {
      f32x4 q2n[2]{};
      if (ktp < 7) {  // compute next q chunk BEFORE the wall
#pragma unroll
        for (int k2 = 0; k2 < 8; ++k2) {
          q2n[0] = MFMA(aeK[k2], wfrag(wp + W_ATTN, k2, 2 * ktp + 2), q2n[0]);
          q2n[1] = MFMA(aeK[k2], wfrag(wp + W_ATTN, k2, 2 * ktp + 3), q2n[1]);
        }
      }
      asm volatile("s_waitcnt lgkmcnt(0)" ::: "memory");
      half8 qb = *(const half8*)(ATTp + (8 + 2 * wv + (ktp & 1)) * 512 + lane * 8);
      if (ktp < 7) stQ(q2n, (ktp + 1) & 1);
#pragma unroll
      for (int rt = 0; rt < 4; ++rt) sc[rt] = MFMA(ldA(R0, ktp, rt), qb, sc[rt]);
    }
    // softmax over row (16wv+c), spread across lanes {g*16+c}
    float m = sc[0][0];
#pragma unroll
    for (int rt = 0; rt < 4; ++rt)
#pragma unroll
      for (int r = 0; r < 4; ++r) m = fmaxf(m, sc[rt][r]);
    m = fmaxf(m, __shfl_xor(m, 16));
    m = fmaxf(m, __shfl_xor(m, 32));
    float e[4][4], s = 0.f;
#pragma unroll
    for (int rt = 0; rt < 4; ++rt)
#pragma unroll
      for (int r = 0; r < 4; ++r) {
        e[rt][r] = __expf(sc[rt][r] - m);
        s += e[rt][r];
      }
    s += __shfl_xor(s, 16);
    s += __shfl_xor(s, 32);
    float inv = 1.0f / s;
    // prefetch P5's kt=0 weights (consumed after B4)
#pragma unroll
    for (int nt = 0; nt < 4; ++nt) {
      pf5g[nt] = wfrag(wp + W_GC1, 0, 4 * wv + nt);
      pf5n[nt] = wfrag(wp + W_NN1, 0, 4 * wv + nt);
    }
    float* ao = attn_out + ((size_t)bb * NA + 16 * wv + c) * NA;
#pragma unroll
    for (int rt = 0; rt < 4; ++rt) {
      f32x4 vv;
      half4_t hh;
#pragma unroll
      for (int r = 0; r < 4; ++r) {
        vv[r] = e[rt][r] * inv;
        hh[r] = (_Float16)vv[r];
      }
      *(f32x4*)(ao + 16 * rt + 4 * g) = vv;
      int fi = (rt >> 1) * 4 + wv;
      int lanep = (2 * (rt & 1) + (g >> 1)) * 16 + c;
      *(half4_t*)(ATTp + fi * 512 + lanep * 8 + 4 * (g & 1)) = hh;
    }
  }
  BAR();  // B4: emb reads done; ATT frags 0..7 complete
  // ===== P5 fused pass over x (LDS): xg1 = x@gc1+b; nn1 = relu(x@nn1+b) =====
  half4_t r1h[4][4];
  {
    f32x4 aG[4][4]{}, aN[4][4]{};
#pragma unroll
    for (int kt = 0; kt < 4; ++kt) {
      half8 af[4], b1[4], b2[4];
#pragma unroll
      for (int rt = 0; rt < 4; ++rt) af[rt] = ldA(X, kt, rt);
#pragma unroll
      for (int nt = 0; nt < 4; ++nt)
        b1[nt] = (kt == 0) ? pf5g[nt] : wfrag(wp + W_GC1, kt, 4 * wv + nt);
#pragma unroll
      for (int nt = 0; nt < 4; ++nt)
        b2[nt] = (kt == 0) ? pf5n[nt] : wfrag(wp + W_NN1, kt, 4 * wv + nt);
#pragma unroll
      for (int rt = 0; rt < 4; ++rt)
#pragma unroll
        for (int nt = 0; nt < 4; ++nt) {
          aG[rt][nt] = MFMA(af[rt], b1[nt], aG[rt][nt]);
          aN[rt][nt] = MFMA(af[rt], b2[nt], aN[rt][nt]);
        }
    }
    ep_storeB(aG, b_gc1);  // xg1 -> R0 (over emb; safe after B4)
#pragma unroll
    for (int nt = 0; nt < 4; ++nt) {
      float bv = b_nn1[64 * wv + 16 * nt + c];
#pragma unroll
      for (int rt = 0; rt < 4; ++rt)
#pragma unroll
        for (int r = 0; r < 4; ++r)
          r1h[rt][nt][r] = (_Float16)fmaxf(aN[rt][nt][r] + bv, 0.f);
    }
    // prefetch P7's kt=0,1 weights (consumed after B7)
#pragma unroll
    for (int s2 = 0; s2 < 2; ++s2)
#pragma unroll
      for (int nt = 0; nt < 4; ++nt) {
        pf7n[s2][nt] = wfrag(wp + W_NN2, s2, 4 * wv + nt);
        pf7g[s2][nt] = wfrag(wp + W_GC2, s2, 4 * wv + nt);
      }
  }
  BAR();  // B5: xg1 visible to all waves
  // ===== P6: feat = (relu(attn@xg1) + nn1)/64 -> R0 =====
  {
    f32x4 a1[4][4]{};
    mm_att(a1);
    BAR();  // B6: all xg1 reads done
#pragma unroll
    for (int nt = 0; nt < 4; ++nt)
#pragma unroll
      for (int rt = 0; rt < 4; ++rt)
#pragma unroll
        for (int r = 0; r < 4; ++r)
          stA_val(R0, rt, nt, r,
                  (fmaxf(a1[rt][nt][r], 0.f) + (float)r1h[rt][nt][r]) * 0.015625f);
  }
  BAR();  // B7: feat complete
  // ===== P7 fused pass over feat: nn2 -> regs; fg2 = feat@gc2+b -> R0 =====
  half4_t r2h[4][4];
  {
    f32x4 aN2[4][4]{}, aG2[4][4]{};
#pragma unroll
    for (int kt = 0; kt < 8; ++kt) {
      half8 af[4], b1[4], b2[4];
#pragma unroll
      for (int rt = 0; rt < 4; ++rt) af[rt] = ldA(R0, kt, rt);
#pragma unroll
      for (int nt = 0; nt < 4; ++nt)
        b1[nt] = (kt < 2) ? pf7n[kt][nt] : wfrag(wp + W_NN2, kt, 4 * wv + nt);
#pragma unroll
      for (int nt = 0; nt < 4; ++nt)
        b2[nt] = (kt < 2) ? pf7g[kt][nt] : wfrag(wp + W_GC2, kt, 4 * wv + nt);
#pragma unroll
      for (int rt = 0; rt < 4; ++rt)
#pragma unroll
        for (int nt = 0; nt < 4; ++nt) {
          aN2[rt][nt] = MFMA(af[rt], b1[nt], aN2[rt][nt]);
          aG2[rt][nt] = MFMA(af[rt], b2[nt], aG2[rt][nt]);
        }
    }
#pragma unroll
    for (int nt = 0; nt < 4; ++nt) {
      float bv = b_nn2[64 * wv + 16 * nt + c];
#pragma unroll
      for (int rt = 0; rt < 4; ++rt)
#pragma unroll
        for (int r = 0; r < 4; ++r)
          r2h[rt][nt][r] = (_Float16)fmaxf(aN2[rt][nt][r] + bv, 0.f);
    }
    BAR();  // B8: all feat reads done
    ep_storeB(aG2, b_gc2);  // fg2 -> R0
  }
  BAR();  // B9
  // ===== P8: out = (relu(attn@fg2) + nn2)/64 -> global =====
  {
    f32x4 a1[4][4]{};
    mm_att(a1);
    float* ob = out + (size_t)bb * NA * HID;
#pragma unroll
    for (int nt = 0; nt < 4; ++nt)
#pragma unroll
      for (int rt = 0; rt < 4; ++rt)
#pragma unroll
        for (int r = 0; r < 4; ++r)
          ob[(size_t)(16 * rt + 4 * g + r) * HID + 64 * wv + 16 * nt + c] =
              (fmaxf(a1[rt][nt][r], 0.f) + (float)r2h[rt][nt][r]) * 0.015625f;
  }
}

extern "C" void kernel_launch(void* const* d_in, const int* in_sizes, int n_in,
                              void* d_out, int out_size, void* d_ws, size_t ws_size,
                              hipStream_t stream) {
  const float* x = (const float*)d_in[0];
  const float* enc_w1 = (const float*)d_in[1];
  const float* enc_b1 = (const float*)d_in[2];
  const float* enc_w2 = (const float*)d_in[3];
  const float* enc_b2 = (const float*)d_in[4];
  const float* attn_w = (const float*)d_in[5];
  const float* gc1_w = (const float*)d_in[6];
  const float* gc1_b = (const float*)d_in[7];
  const float* nn1_w = (const float*)d_in[8];
  const float* nn1_b = (const float*)d_in[9];
  const float* gc2_w = (const float*)d_in[10];
  const float* gc2_b = (const float*)d_in[11];
  const float* nn2_w = (const float*)d_in[12];
  const float* nn2_b = (const float*)d_in[13];
  // d_in[14] = n_agents (=64, compile-time constant)

  _Float16* wp = (_Float16*)d_ws;
  float* out = (float*)d_out;
  float* attn_o = out + (size_t)NBATCH * NA * HID;

  pack_all<<<176, 256, 0, stream>>>(enc_w1, enc_w2, attn_w, gc1_w, nn1_w, gc2_w,
                                    nn2_w, wp);
  dicg_main<<<NBATCH, 256, SMEM_BYTES, stream>>>(
      x, enc_b1, enc_b2, gc1_b, nn1_b, gc2_b, nn2_b, wp, out, attn_o);
}

// Round 11
// 154.904 us; speedup vs baseline: 1.5343x; 1.0097x over previous
//
#include <hip/hip_runtime.h>

typedef _Float16 half8 __attribute__((ext_vector_type(8)));
typedef _Float16 half4_t __attribute__((ext_vector_type(4)));
typedef float f32x4 __attribute__((ext_vector_type(4)));

#define NBATCH 2048
#define NA 64
#define SA 128
#define HID 256

// LDS halves: X 8192 (16KB) | R0 16384 (32KB) | ATT 8192 (16KB) = 65536 B
// ATT frags 0..7: attn A-frags; frags 8..15: per-wave q double-buffer slots.
#define OFF_X 0
#define OFF_R0 8192
#define OFF_ATT (8192 + 16384)
#define SMEM_BYTES ((8192 + 16384 + 8192) * 2)

// packed fp16 weight offsets (halves) inside d_ws
#define W_ENC1 0
#define W_ENC2 (W_ENC1 + 128 * 256)
#define W_ATTN (W_ENC2 + 256 * 256)
#define W_GC1 (W_ATTN + 256 * 256)
#define W_NN1 (W_GC1 + 128 * 256)
#define W_GC2 (W_NN1 + 128 * 256)
#define W_NN2 (W_GC2 + 256 * 256)

#define MFMA(a, b, cacc) __builtin_amdgcn_mfma_f32_16x16x32_f16((a), (b), (cacc), 0, 0, 0)

// lgkmcnt-only barrier. All cross-wave dataflow at these barriers is through
// LDS (lgkm-counted). __syncthreads would also drain vmcnt(0), killing any
// in-flight global weight prefetch; this keeps it alive across the barrier.
#define BAR()                                            \
  do {                                                   \
    asm volatile("s_waitcnt lgkmcnt(0)" ::: "memory");   \
    __builtin_amdgcn_s_barrier();                        \
  } while (0)

// One launch packs all 7 weights into MFMA B-fragment order fp16.
// dst[((kt*16+nt)*64+lane)*8 + j] = W[kt*32 + (lane>>4)*8 + j][nt*16 + (lane&15)]
__global__ void pack_all(const float* __restrict__ e1, const float* __restrict__ e2,
                         const float* __restrict__ aw, const float* __restrict__ g1,
                         const float* __restrict__ n1, const float* __restrict__ g2,
                         const float* __restrict__ n2, _Float16* __restrict__ dst) {
  int b = (int)blockIdx.x;
  const float* src;
  int off;
  if (b < 16) { src = e1; off = W_ENC1; }
  else if (b < 48) { src = e2; off = W_ENC2; b -= 16; }
  else if (b < 80) { src = aw; off = W_ATTN; b -= 48; }
  else if (b < 96) { src = g1; off = W_GC1; b -= 80; }
  else if (b < 112) { src = n1; off = W_NN1; b -= 96; }
  else if (b < 144) { src = g2; off = W_GC2; b -= 112; }
  else { src = n2; off = W_NN2; b -= 144; }
  int t = b * 256 + (int)threadIdx.x;
  int lane = t & 63, frag = t >> 6;
  int nt = frag & 15, kt = frag >> 4;
  int g = lane >> 4, c = lane & 15;
  half8 h;
#pragma unroll
  for (int j = 0; j < 8; ++j)
    h[j] = (_Float16)src[(size_t)(kt * 32 + g * 8 + j) * 256 + nt * 16 + c];
  *(half8*)(dst + off + (size_t)t * 8) = h;
}

__global__ __launch_bounds__(256, 2) void dicg_main(
    const float* __restrict__ x, const float* __restrict__ b_enc1,
    const float* __restrict__ b_enc2, const float* __restrict__ b_gc1,
    const float* __restrict__ b_nn1, const float* __restrict__ b_gc2,
    const float* __restrict__ b_nn2, const _Float16* __restrict__ wp,
    float* __restrict__ out, float* __restrict__ attn_out) {
  extern __shared__ _Float16 sm[];
  _Float16* X = sm + OFF_X;        // x fp16 A-frags (written P1, read P5)
  _Float16* R0 = sm + OFF_R0;      // h1 -> emb -> xg1T -> feat -> fg2T
  _Float16* ATTp = sm + OFF_ATT;   // frags 0..7: attn A-frags; 8..15: q dbuf

  const int tid = (int)threadIdx.x;
  const int wv = tid >> 6;   // wave 0..3 (owns output cols 64*wv..+63)
  const int lane = tid & 63;
  const int g = lane >> 4;   // 0..3
  const int c = lane & 15;   // 0..15
  const int bb = (int)blockIdx.x;
  const float* __restrict__ xb = x + (size_t)bb * (NA * SA);

  // ---- fragment-linear LDS loads (conflict-free: lane*16B contiguous) ----
  auto ldA = [&](const _Float16* p, int kt, int rt) -> half8 {
    return *(const half8*)(p + (kt * 4 + rt) * 512 + lane * 8);
  };
  auto ldB = [&](const _Float16* p, int kt, int ct) -> half8 {
    return *(const half8*)(p + (kt * 16 + ct) * 512 + lane * 8);
  };
  auto wfrag = [&](const _Float16* wb, int kt, int ntg) -> half8 {
    return *(const half8*)(wb + ((size_t)(kt * 16 + ntg) * 64 + lane) * 8);
  };
  auto xfrag = [&](int r0, int k0) -> half8 {
    const float* p = xb + (r0 + c) * SA + k0 + g * 8;
    f32x4 u = *(const f32x4*)p;
    f32x4 v = *(const f32x4*)(p + 4);
    half8 h;
    h[0] = (_Float16)u[0]; h[1] = (_Float16)u[1];
    h[2] = (_Float16)u[2]; h[3] = (_Float16)u[3];
    h[4] = (_Float16)v[0]; h[5] = (_Float16)v[1];
    h[6] = (_Float16)v[2]; h[7] = (_Float16)v[3];
    return h;
  };

  // ---- C-layout -> packed-LDS stores ----
  // producer lane holds D[16rt+4g+r][64wv+16nt+c]
  auto stA_val = [&](_Float16* dst, int rt, int nt, int r, float v) {
    int kt = 2 * wv + (nt >> 1);
    int lanep = (2 * (nt & 1) + (c >> 3)) * 16 + 4 * g + r;
    dst[(kt * 4 + rt) * 512 + lanep * 8 + (c & 7)] = (_Float16)v;
  };
  auto ep_storeA = [&](f32x4(&acc)[4][4], const float* bias, bool dorelu) {
#pragma unroll
    for (int nt = 0; nt < 4; ++nt) {
      float bv = bias[64 * wv + 16 * nt + c];
#pragma unroll
      for (int rt = 0; rt < 4; ++rt)
#pragma unroll
        for (int r = 0; r < 4; ++r) {
          float y = acc[rt][nt][r] + bv;
          if (dorelu) y = fmaxf(y, 0.f);
          stA_val(R0, rt, nt, r, y);
        }
    }
  };
  // B-packed store, vectorized: 4 consecutive halves per (rt,nt)
  auto ep_storeB = [&](f32x4(&acc)[4][4], const float* bias) {
#pragma unroll
    for (int nt = 0; nt < 4; ++nt) {
      float bv = bias[64 * wv + 16 * nt + c];
#pragma unroll
      for (int rt = 0; rt < 4; ++rt) {
        half4_t h;
#pragma unroll
        for (int r = 0; r < 4; ++r) h[r] = (_Float16)(acc[rt][nt][r] + bv);
        int fi = (rt >> 1) * 16 + 4 * wv + nt;
        int lanep = (2 * (rt & 1) + (g >> 1)) * 16 + c;
        *(half4_t*)(R0 + fi * 512 + lanep * 8 + 4 * (g & 1)) = h;
      }
    }
  };
  // q chunk C-layout -> per-wave double-buffered B-frag scratch (frags 8..15)
  auto stQ = [&](const f32x4(&q2)[2], int s) {
    _Float16* base = ATTp + (8 + 2 * wv + s) * 512;
#pragma unroll
    for (int nt2 = 0; nt2 < 2; ++nt2)
#pragma unroll
      for (int r = 0; r < 4; ++r)
        base[((2 * nt2 + (c >> 3)) * 16 + 4 * g + r) * 8 + (c & 7)] = (_Float16)q2[nt2][r];
  };
  auto mm_att = [&](f32x4(&acc)[4][4]) {
#pragma unroll
    for (int kt = 0; kt < 2; ++kt) {
      half8 af[4], bf[4];
#pragma unroll
      for (int rt = 0; rt < 4; ++rt) af[rt] = ldA(ATTp, kt, rt);
#pragma unroll
      for (int nt = 0; nt < 4; ++nt) bf[nt] = ldB(R0, kt, 4 * wv + nt);
#pragma unroll
      for (int rt = 0; rt < 4; ++rt)
#pragma unroll
        for (int nt = 0; nt < 4; ++nt) acc[rt][nt] = MFMA(af[rt], bf[nt], acc[rt][nt]);
    }
  };

  // cross-barrier weight prefetch registers
  half8 pf2[4][4];               // P2: W_ENC2 kt=0..3
  half8 pfq[8][2];               // P3: W_ATTN k2=0..7, cols 0,1 (full q-tile 0)
  half8 pf5g[2][4], pf5n[2][4];  // P5: W_GC1 / W_NN1 kt=0,1
  half8 pf7n[3][4], pf7g[3][4];  // P7: W_NN2 / W_GC2 kt=0,1 (P5) + kt=2 (P6)

  // ========== P1: h1 = relu(x@enc1+b1) -> R0; stage x fp16 frags -> X ==========
  {
    f32x4 acc[4][4]{};
#pragma unroll
    for (int kt = 0; kt < 4; ++kt) {
      half8 af[4], bf[4];
#pragma unroll
      for (int rt = 0; rt < 4; ++rt) af[rt] = xfrag(16 * rt, kt * 32);
#pragma unroll
      for (int nt = 0; nt < 4; ++nt) bf[nt] = wfrag(wp + W_ENC1, kt, 4 * wv + nt);
      if (kt == wv) {  // each wave stages one kt of x
#pragma unroll
        for (int rt = 0; rt < 4; ++rt)
          *(half8*)(X + (kt * 4 + rt) * 512 + lane * 8) = af[rt];
      }
#pragma unroll
      for (int rt = 0; rt < 4; ++rt)
#pragma unroll
        for (int nt = 0; nt < 4; ++nt) acc[rt][nt] = MFMA(af[rt], bf[nt], acc[rt][nt]);
    }
    // prefetch P2's first four K-tiles of W_ENC2 (consumed after B1)
#pragma unroll
    for (int s = 0; s < 4; ++s)
#pragma unroll
      for (int nt = 0; nt < 4; ++nt) pf2[s][nt] = wfrag(wp + W_ENC2, s, 4 * wv + nt);
    ep_storeA(acc, b_enc1, true);
  }
  BAR();  // B1
  // ========== P2: emb = relu(h1@enc2+b2), in-place ==========
  {
    f32x4 acc[4][4]{};
#pragma unroll
    for (int kt = 0; kt < 8; ++kt) {
      half8 af[4], bf[4];
#pragma unroll
      for (int rt = 0; rt < 4; ++rt) af[rt] = ldA(R0, kt, rt);
#pragma unroll
      for (int nt = 0; nt < 4; ++nt)
        bf[nt] = (kt < 4) ? pf2[kt][nt] : wfrag(wp + W_ENC2, kt, 4 * wv + nt);
#pragma unroll
      for (int rt = 0; rt < 4; ++rt)
#pragma unroll
        for (int nt = 0; nt < 4; ++nt) acc[rt][nt] = MFMA(af[rt], bf[nt], acc[rt][nt]);
    }
    // prefetch the FULL q-tile-0 of W_ATTN (consumed after B3)
#pragma unroll
    for (int k2 = 0; k2 < 8; ++k2) {
      pfq[k2][0] = wfrag(wp + W_ATTN, k2, 0);
      pfq[k2][1] = wfrag(wp + W_ATTN, k2, 1);
    }
    BAR();  // B2: all h1 reads done
    ep_storeA(acc, b_enc2, true);
  }
  BAR();  // B3
  // ===== P3+P4: scoresT = emb @ qT (q dbuf-pipelined), softmax =====
  {
    half8 aeK[8];
#pragma unroll
    for (int k2 = 0; k2 < 8; ++k2) aeK[k2] = ldA(R0, k2, wv);
    f32x4 sc[4]{};
    {
      f32x4 q2[2]{};
#pragma unroll
      for (int k2 = 0; k2 < 8; ++k2) {
        q2[0] = MFMA(aeK[k2], pfq[k2][0], q2[0]);
        q2[1] = MFMA(aeK[k2], pfq[k2][1], q2[1]);
      }
      stQ(q2, 0);
    }
#pragma unroll
    for (int ktp = 0; ktp < 8; ++ktp) {
      f32x4 q2n[2]{};
      if (ktp < 7) {  // compute next q chunk BEFORE the wall
#pragma unroll
        for (int k2 = 0; k2 < 8; ++k2) {
          q2n[0] = MFMA(aeK[k2], wfrag(wp + W_ATTN, k2, 2 * ktp + 2), q2n[0]);
          q2n[1] = MFMA(aeK[k2], wfrag(wp + W_ATTN, k2, 2 * ktp + 3), q2n[1]);
        }
      }
      asm volatile("s_waitcnt lgkmcnt(0)" ::: "memory");
      half8 qb = *(const half8*)(ATTp + (8 + 2 * wv + (ktp & 1)) * 512 + lane * 8);
      if (ktp < 7) stQ(q2n, (ktp + 1) & 1);
#pragma unroll
      for (int rt = 0; rt < 4; ++rt) sc[rt] = MFMA(ldA(R0, ktp, rt), qb, sc[rt]);
    }
    // softmax over row (16wv+c), spread across lanes {g*16+c}
    float m = sc[0][0];
#pragma unroll
    for (int rt = 0; rt < 4; ++rt)
#pragma unroll
      for (int r = 0; r < 4; ++r) m = fmaxf(m, sc[rt][r]);
    m = fmaxf(m, __shfl_xor(m, 16));
    m = fmaxf(m, __shfl_xor(m, 32));
    float e[4][4], s = 0.f;
#pragma unroll
    for (int rt = 0; rt < 4; ++rt)
#pragma unroll
      for (int r = 0; r < 4; ++r) {
        e[rt][r] = __expf(sc[rt][r] - m);
        s += e[rt][r];
      }
    s += __shfl_xor(s, 16);
    s += __shfl_xor(s, 32);
    float inv = 1.0f / s;
    // prefetch P5's kt=0,1 weights (consumed after B4)
#pragma unroll
    for (int s5 = 0; s5 < 2; ++s5)
#pragma unroll
      for (int nt = 0; nt < 4; ++nt) {
        pf5g[s5][nt] = wfrag(wp + W_GC1, s5, 4 * wv + nt);
        pf5n[s5][nt] = wfrag(wp + W_NN1, s5, 4 * wv + nt);
      }
    float* ao = attn_out + ((size_t)bb * NA + 16 * wv + c) * NA;
#pragma unroll
    for (int rt = 0; rt < 4; ++rt) {
      f32x4 vv;
      half4_t hh;
#pragma unroll
      for (int r = 0; r < 4; ++r) {
        vv[r] = e[rt][r] * inv;
        hh[r] = (_Float16)vv[r];
      }
      *(f32x4*)(ao + 16 * rt + 4 * g) = vv;
      int fi = (rt >> 1) * 4 + wv;
      int lanep = (2 * (rt & 1) + (g >> 1)) * 16 + c;
      *(half4_t*)(ATTp + fi * 512 + lanep * 8 + 4 * (g & 1)) = hh;
    }
  }
  BAR();  // B4: emb reads done; ATT frags 0..7 complete
  // ===== P5 fused pass over x (LDS): xg1 = x@gc1+b; nn1 = relu(x@nn1+b) =====
  half4_t r1h[4][4];
  {
    f32x4 aG[4][4]{}, aN[4][4]{};
#pragma unroll
    for (int kt = 0; kt < 4; ++kt) {
      half8 af[4], b1[4], b2[4];
#pragma unroll
      for (int rt = 0; rt < 4; ++rt) af[rt] = ldA(X, kt, rt);
#pragma unroll
      for (int nt = 0; nt < 4; ++nt)
        b1[nt] = (kt < 2) ? pf5g[kt][nt] : wfrag(wp + W_GC1, kt, 4 * wv + nt);
#pragma unroll
      for (int nt = 0; nt < 4; ++nt)
        b2[nt] = (kt < 2) ? pf5n[kt][nt] : wfrag(wp + W_NN1, kt, 4 * wv + nt);
#pragma unroll
      for (int rt = 0; rt < 4; ++rt)
#pragma unroll
        for (int nt = 0; nt < 4; ++nt) {
          aG[rt][nt] = MFMA(af[rt], b1[nt], aG[rt][nt]);
          aN[rt][nt] = MFMA(af[rt], b2[nt], aN[rt][nt]);
        }
    }
    ep_storeB(aG, b_gc1);  // xg1 -> R0 (over emb; safe after B4)
#pragma unroll
    for (int nt = 0; nt < 4; ++nt) {
      float bv = b_nn1[64 * wv + 16 * nt + c];
#pragma unroll
      for (int rt = 0; rt < 4; ++rt)
#pragma unroll
        for (int r = 0; r < 4; ++r)
          r1h[rt][nt][r] = (_Float16)fmaxf(aN[rt][nt][r] + bv, 0.f);
    }
    // prefetch P7's kt=0,1 weights (consumed after B7)
#pragma unroll
    for (int s2 = 0; s2 < 2; ++s2)
#pragma unroll
      for (int nt = 0; nt < 4; ++nt) {
        pf7n[s2][nt] = wfrag(wp + W_NN2, s2, 4 * wv + nt);
        pf7g[s2][nt] = wfrag(wp + W_GC2, s2, 4 * wv + nt);
      }
  }
  BAR();  // B5: xg1 visible to all waves
  // ===== P6: feat = (relu(attn@xg1) + nn1)/64 -> R0 =====
  {
    // prefetch P7's kt=2 weights (hides under mm_att + B6/B7 barriers)
#pragma unroll
    for (int nt = 0; nt < 4; ++nt) {
      pf7n[2][nt] = wfrag(wp + W_NN2, 2, 4 * wv + nt);
      pf7g[2][nt] = wfrag(wp + W_GC2, 2, 4 * wv + nt);
    }
    f32x4 a1[4][4]{};
    mm_att(a1);
    BAR();  // B6: all xg1 reads done
#pragma unroll
    for (int nt = 0; nt < 4; ++nt)
#pragma unroll
      for (int rt = 0; rt < 4; ++rt)
#pragma unroll
        for (int r = 0; r < 4; ++r)
          stA_val(R0, rt, nt, r,
                  (fmaxf(a1[rt][nt][r], 0.f) + (float)r1h[rt][nt][r]) * 0.015625f);
  }
  BAR();  // B7: feat complete
  // ===== P7 fused pass over feat: nn2 -> regs; fg2 = feat@gc2+b -> R0 =====
  half4_t r2h[4][4];
  {
    f32x4 aN2[4][4]{}, aG2[4][4]{};
#pragma unroll
    for (int kt = 0; kt < 8; ++kt) {
      half8 af[4], b1[4], b2[4];
#pragma unroll
      for (int rt = 0; rt < 4; ++rt) af[rt] = ldA(R0, kt, rt);
#pragma unroll
      for (int nt = 0; nt < 4; ++nt)
        b1[nt] = (kt < 3) ? pf7n[kt][nt] : wfrag(wp + W_NN2, kt, 4 * wv + nt);
#pragma unroll
      for (int nt = 0; nt < 4; ++nt)
        b2[nt] = (kt < 3) ? pf7g[kt][nt] : wfrag(wp + W_GC2, kt, 4 * wv + nt);
#pragma unroll
      for (int rt = 0; rt < 4; ++rt)
#pragma unroll
        for (int nt = 0; nt < 4; ++nt) {
          aN2[rt][nt] = MFMA(af[rt], b1[nt], aN2[rt][nt]);
          aG2[rt][nt] = MFMA(af[rt], b2[nt], aG2[rt][nt]);
        }
    }
#pragma unroll
    for (int nt = 0; nt < 4; ++nt) {
      float bv = b_nn2[64 * wv + 16 * nt + c];
#pragma unroll
      for (int rt = 0; rt < 4; ++rt)
#pragma unroll
        for (int r = 0; r < 4; ++r)
          r2h[rt][nt][r] = (_Float16)fmaxf(aN2[rt][nt][r] + bv, 0.f);
    }
    BAR();  // B8: all feat reads done
    ep_storeB(aG2, b_gc2);  // fg2 -> R0
  }
  BAR();  // B9
  // ===== P8: out = (relu(attn@fg2) + nn2)/64 -> global =====
  {
    f32x4 a1[4][4]{};
    mm_att(a1);
    float* ob = out + (size_t)bb * NA * HID;
#pragma unroll
    for (int nt = 0; nt < 4; ++nt)
#pragma unroll
      for (int rt = 0; rt < 4; ++rt)
#pragma unroll
        for (int r = 0; r < 4; ++r)
          ob[(size_t)(16 * rt + 4 * g + r) * HID + 64 * wv + 16 * nt + c] =
              (fmaxf(a1[rt][nt][r], 0.f) + (float)r2h[rt][nt][r]) * 0.015625f;
  }
}

extern "C" void kernel_launch(void* const* d_in, const int* in_sizes, int n_in,
                              void* d_out, int out_size, void* d_ws, size_t ws_size,
                              hipStream_t stream) {
  const float* x = (const float*)d_in[0];
  const float* enc_w1 = (const float*)d_in[1];
  const float* enc_b1 = (const float*)d_in[2];
  const float* enc_w2 = (const float*)d_in[3];
  const float* enc_b2 = (const float*)d_in[4];
  const float* attn_w = (const float*)d_in[5];
  const float* gc1_w = (const float*)d_in[6];
  const float* gc1_b = (const float*)d_in[7];
  const float* nn1_w = (const float*)d_in[8];
  const float* nn1_b = (const float*)d_in[9];
  const float* gc2_w = (const float*)d_in[10];
  const float* gc2_b = (const float*)d_in[11];
  const float* nn2_w = (const float*)d_in[12];
  const float* nn2_b = (const float*)d_in[13];
  // d_in[14] = n_agents (=64, compile-time constant)

  _Float16* wp = (_Float16*)d_ws;
  float* out = (float*)d_out;
  float* attn_o = out + (size_t)NBATCH * NA * HID;

  pack_all<<<176, 256, 0, stream>>>(enc_w1, enc_w2, attn_w, gc1_w, nn1_w, gc2_w,
                                    nn2_w, wp);
  dicg_main<<<NBATCH, 256, SMEM_BYTES, stream>>>(
      x, enc_b1, enc_b2, gc1_b, nn1_b, gc2_b, nn2_b, wp, out, attn_o);
}